// Round 6
// baseline (106.017 us; speedup 1.0000x reference)
//
#include <hip/hip_runtime.h>
#include <math.h>

#define NNODES 512
#define CIN 8
#define COUT 8
#define RR 8
#define BTB 2                          // bt items per block (2 waves per bt)
#define GUARD 64                       // zeroed guard node-slots each side
#define SLOTS (GUARD + NNODES + GUARD) // 640 node slots per bt
#define SLAB_HW (SLOTS * 8)            // 5120 halfwords per bt (16 B per node slot)
#define LDS_HW (BTB * SLAB_HW)         // 10240 hw = 20480 B

typedef __attribute__((ext_vector_type(8))) short short8;
typedef __attribute__((ext_vector_type(4))) float floatx4;

__device__ __forceinline__ unsigned int pack_bf16(float a, float b) {
    unsigned int ua = __float_as_uint(a);
    unsigned int ub = __float_as_uint(b);
    ua = (ua + 0x7fffu + ((ua >> 16) & 1u)) >> 16;
    ub = (ub + 0x7fffu + ((ub >> 16) & 1u)) & 0xffff0000u;
    return ua | ub;
}

// Single-launch kernel.
// K = tap*8 + c; MFMA i covers taps {4i..4i+3}; quad q holds tap 4i+q.
// taps: 0 center, 1 d-, 2 d+, 3 h-, 4 h+, 5 w-, 6 w+, 7..14 g0..g7, 15 zero.
// Per-quad random columns: rA=(q+1)&3 (slots i2 for q<3, i1 for q3),
//                          rB=rA+4    (slots i3 for q<3, i2 for q3); q3 i3 = zero.
__global__ __launch_bounds__(256) void hybrid3d_v4(
    const float* __restrict__ x,
    const float* __restrict__ conv_w,
    const float* __restrict__ conv_b,
    const float* __restrict__ mix_w,
    const float* __restrict__ mix_b,
    const float* __restrict__ alpha_p,
    const int*   __restrict__ rand_idx,
    float* __restrict__ out)
{
    __shared__ unsigned short lds16[LDS_HW];
    float* wfold = (float*)lds16;          // aliased scratch during weight-fold phase

    const int tid  = threadIdx.x;
    const int wave = tid >> 6;
    const int lane = tid & 63;
    const int quad = lane >> 4;
    const int r16  = lane & 15;
    const int btl  = wave >> 1;            // bt within block
    const int half = wave & 1;             // node-half for this wave

    const float a = 1.0f / (1.0f + expf(-alpha_p[0]));

    // ---- phase 1: fold weights into LDS scratch (tap = compile-time) ----
    // wfold[(o*8+c)*15 + tap]; stencil tap->conv_w 27-offset: c=13,d-=4,d+=22,h-=10,h+=16,w-=12,w+=14
    if (tid < 64) {   // tid = o*8+c
        const float* cw = conv_w + tid * 27;
        const float* mw = mix_w + tid * RR;
        float* wf = wfold + tid * 15;
        wf[0] = a * cw[13];
        wf[1] = a * cw[4];
        wf[2] = a * cw[22];
        wf[3] = a * cw[10];
        wf[4] = a * cw[16];
        wf[5] = a * cw[12];
        wf[6] = a * cw[14];
        const float oma = 1.0f - a;
#pragma unroll
        for (int r = 0; r < RR; ++r) wf[7 + r] = oma * mw[r];
    }
    const float bias = (r16 < 8) ? (a * conv_b[r16] + (1.0f - a) * mix_b[r16]) : 0.0f;
    __syncthreads();

    // ---- phase 2: B-fragments from wfold ----
    short8 bfrag[4];
#pragma unroll
    for (int i = 0; i < 4; ++i) {
        const int tap = 4 * i + quad;
        union { unsigned int u[4]; short8 s; } bf;
#pragma unroll
        for (int jp = 0; jp < 4; ++jp) {
            const int c0 = 2 * jp, c1 = 2 * jp + 1;
            float f0 = (r16 < 8 && tap < 15) ? wfold[(r16 * CIN + c0) * 15 + tap] : 0.0f;
            float f1 = (r16 < 8 && tap < 15) ? wfold[(r16 * CIN + c1) * 15 + tap] : 0.0f;
            bf.u[jp] = pack_bf16(f0, f1);
        }
        bfrag[i] = bf.s;
    }
    __syncthreads();   // before overwriting the aliased scratch

    // ---- phase 3: zero guards + stage x -> node-major bf16 slots ----
    {
        const int b = tid >> 7;
        const int s = tid & 127;
        const int slot = (s < GUARD) ? s : (NNODES + s);   // 0..63 | 576..639
        *(uint4*)&lds16[b * SLAB_HW + slot * 8] = make_uint4(0u, 0u, 0u, 0u);
    }
    const float* xg = x + ((size_t)blockIdx.x * BTB + btl) * (CIN * NNODES);
    unsigned short* slab = lds16 + btl * SLAB_HW;
#pragma unroll
    for (int j = 0; j < 4; ++j) {
        const int n = half * 256 + j * 64 + lane;
        float v[8];
#pragma unroll
        for (int c = 0; c < 8; ++c) v[c] = xg[c * NNODES + n];
        uint4 pk;
        pk.x = pack_bf16(v[0], v[1]);
        pk.y = pack_bf16(v[2], v[3]);
        pk.z = pack_bf16(v[4], v[5]);
        pk.w = pack_bf16(v[6], v[7]);
        *(uint4*)&slab[(GUARD + n) * 8] = pk;
    }
    __syncthreads();

    // ---- phase 4: main loop, inline offsets ----
    const char* slabp = (const char*)slab;
    float* outb = out + ((size_t)blockIdx.x * BTB + btl) * (COUT * NNODES);

    const int  rA   = (quad + 1) & 3;          // random column A
    const bool q3f  = (quad == 3);
    const bool isq0 = (quad == 0);
    // i0 per-quad byte delta: q0 center 0, q1 d- -1024, q2 d+ +1024, q3 h- -128
    const int c0q = (quad == 0) ? 0 : (quad == 1) ? -1024 : (quad == 2) ? 1024 : -128;
    // i1 per-quad byte delta: q0 h+ +128, q1 w- -16, q2 w+ +16 (q3 unused)
    const int c1q = (quad == 0) ? 128 : (quad == 1) ? -16 : 16;
    const int w   = r16 & 7;                   // loop-invariant w coordinate
    const bool p1w = (quad == 1) ? (w > 0) : (quad == 2) ? (w < 7) : false;
    const int* rrow = rand_idx + rA;           // + m*8 per iter

#pragma unroll 2
    for (int tt = 0; tt < 16; ++tt) {
        const int t = half * 16 + tt;
        const int m = t * 16 + r16;
        const int hh = (m >> 3) & 7;
        const int base = 1024 + m * 16;        // byte offset of center slot

        const int gA = rrow[m * RR];           // rand_idx[m*8 + rA]
        const int gB = rrow[m * RR + 4];       // rand_idx[m*8 + rA + 4]
        const int offA = 1024 + gA * 16;
        const int offB = 1024 + gB * 16;

        const bool p0 = (!q3f) || (hh > 0);
        const int off0 = p0 ? (base + c0q) : 0;
        const bool p1 = isq0 ? (hh < 7) : p1w;
        const int off1 = q3f ? offA : (p1 ? (base + c1q) : 0);
        const int off2 = q3f ? offB : offA;
        const int off3 = q3f ? 0 : offB;

        union { uint4 u; short8 s; } r0, r1, r2, r3;   // 4x ds_read_b128
        r0.u = *(const uint4*)(slabp + off0);
        r1.u = *(const uint4*)(slabp + off1);
        r2.u = *(const uint4*)(slabp + off2);
        r3.u = *(const uint4*)(slabp + off3);

        floatx4 acc_a = {bias, bias, bias, bias};
        floatx4 acc_b = {0.0f, 0.0f, 0.0f, 0.0f};
        acc_a = __builtin_amdgcn_mfma_f32_16x16x32_bf16(r0.s, bfrag[0], acc_a, 0, 0, 0);
        acc_b = __builtin_amdgcn_mfma_f32_16x16x32_bf16(r2.s, bfrag[2], acc_b, 0, 0, 0);
        acc_a = __builtin_amdgcn_mfma_f32_16x16x32_bf16(r1.s, bfrag[1], acc_a, 0, 0, 0);
        acc_b = __builtin_amdgcn_mfma_f32_16x16x32_bf16(r3.s, bfrag[3], acc_b, 0, 0, 0);

        // C/D: col=lane&15 (=o), row=quad*4+reg (node within 16-tile)
        if (r16 < 8) {
            float4 res;
            res.x = acc_a.x + acc_b.x;
            res.y = acc_a.y + acc_b.y;
            res.z = acc_a.z + acc_b.z;
            res.w = acc_a.w + acc_b.w;
            *(float4*)(outb + r16 * NNODES + t * 16 + quad * 4) = res;
        }
    }
}

extern "C" void kernel_launch(void* const* d_in, const int* in_sizes, int n_in,
                              void* d_out, int out_size, void* d_ws, size_t ws_size,
                              hipStream_t stream) {
    const float* x       = (const float*)d_in[0];
    const float* conv_w  = (const float*)d_in[1];
    const float* conv_b  = (const float*)d_in[2];
    const float* mix_w   = (const float*)d_in[3];
    const float* mix_b   = (const float*)d_in[4];
    const float* alpha_p = (const float*)d_in[5];
    const int*   rand_i  = (const int*)d_in[6];
    float* out = (float*)d_out;

    const int BT = in_sizes[0] / (CIN * NNODES);   // 2048

    hybrid3d_v4<<<BT / BTB, 256, 0, stream>>>(x, conv_w, conv_b, mix_w, mix_b,
                                              alpha_p, rand_i, out);
}

// Round 7
// 105.903 us; speedup vs baseline: 1.0011x; 1.0011x over previous
//
#include <hip/hip_runtime.h>
#include <math.h>

#define NNODES 512
#define CIN 8
#define COUT 8
#define RR 8
#define SLAB_HW ((1 + NNODES) * 8 + 8)   // 4112 halfwords = 8224 B (slot 0 = zeros)

typedef __attribute__((ext_vector_type(8))) short short8;
typedef __attribute__((ext_vector_type(4))) float floatx4;

__device__ __forceinline__ unsigned int pack_bf16(float a, float b) {
    unsigned int ua = __float_as_uint(a);
    unsigned int ub = __float_as_uint(b);
    ua = (ua + 0x7fffu + ((ua >> 16) & 1u)) >> 16;
    ub = (ub + 0x7fffu + ((ub >> 16) & 1u)) & 0xffff0000u;
    return ua | ub;
}

// Single-launch. Block = 1 bt (256 thr, 4 waves; wave w does node-tiles w*8..w*8+7).
// LDS: slot 0 = 16B zeros, slots 1..512 = node-major bf16 (8ch x 16B).
// K = tap*8 + c; MFMA i covers taps {4i..4i+3}; quad q holds tap 4i+q.
// taps: 0 center, 1 d-, 2 d+, 3 h-, 4 h+, 5 w-, 6 w+, 7..14 g0..g7, 15 zero.
// Per-quad random cols: rA=(q+1)&3 (i2 for q<3, i1 for q3), rB=rA+4; q3 i3 = zero.
// d = t>>2 is wave-uniform -> d-predicates are scalar; edges redirect to slot 0.
__global__ __launch_bounds__(256, 6) void hybrid3d_v5(
    const float* __restrict__ x,
    const float* __restrict__ conv_w,
    const float* __restrict__ conv_b,
    const float* __restrict__ mix_w,
    const float* __restrict__ mix_b,
    const float* __restrict__ alpha_p,
    const int*   __restrict__ rand_idx,
    float* __restrict__ out)
{
    __shared__ unsigned short lds16[SLAB_HW];
    float* wfold = (float*)lds16;          // 960-float scratch, aliased (tap-major)

    const int tid  = threadIdx.x;
    const int wave = tid >> 6;
    const int lane = tid & 63;
    const int quad = lane >> 4;
    const int r16  = lane & 15;

    const float a = 1.0f / (1.0f + expf(-alpha_p[0]));

    // ---- phase 1: fold weights into LDS scratch, tap-major: wfold[tap*64 + o*8 + c]
    if (tid < 64) {   // tid = o*8+c
        const float* cw = conv_w + tid * 27;
        const float* mw = mix_w + tid * RR;
        const float oma = 1.0f - a;
        // stencil tap -> conv_w 27-offset: c=13, d-=4, d+=22, h-=10, h+=16, w-=12, w+=14
        wfold[0 * 64 + tid] = a * cw[13];
        wfold[1 * 64 + tid] = a * cw[4];
        wfold[2 * 64 + tid] = a * cw[22];
        wfold[3 * 64 + tid] = a * cw[10];
        wfold[4 * 64 + tid] = a * cw[16];
        wfold[5 * 64 + tid] = a * cw[12];
        wfold[6 * 64 + tid] = a * cw[14];
#pragma unroll
        for (int r = 0; r < RR; ++r) wfold[(7 + r) * 64 + tid] = oma * mw[r];
    }
    const float bias = (r16 < 8) ? (a * conv_b[r16] + (1.0f - a) * mix_b[r16]) : 0.0f;
    __syncthreads();

    // ---- phase 2: B-fragments (c-pairs contiguous -> ds_read_b64) ----
    short8 bfrag[4];
#pragma unroll
    for (int i = 0; i < 4; ++i) {
        const int tap = 4 * i + quad;
        union { unsigned int u[4]; short8 s; } bf;
#pragma unroll
        for (int jp = 0; jp < 4; ++jp) {
            float f0 = 0.0f, f1 = 0.0f;
            if (r16 < 8 && tap < 15) {
                const float2 f = *(const float2*)&wfold[tap * 64 + r16 * 8 + 2 * jp];
                f0 = f.x; f1 = f.y;
            }
            bf.u[jp] = pack_bf16(f0, f1);
        }
        bfrag[i] = bf.s;
    }
    __syncthreads();   // before overwriting the aliased scratch

    // ---- phase 3: zero slot 0 + stage x -> node-major bf16 slots ----
    if (tid == 0) *(uint4*)&lds16[0] = make_uint4(0u, 0u, 0u, 0u);
    const float* xg = x + (size_t)blockIdx.x * (CIN * NNODES);
#pragma unroll
    for (int j = 0; j < 2; ++j) {
        const int n = j * 256 + tid;
        float v[8];
#pragma unroll
        for (int c = 0; c < 8; ++c) v[c] = xg[c * NNODES + n];
        uint4 pk;
        pk.x = pack_bf16(v[0], v[1]);
        pk.y = pack_bf16(v[2], v[3]);
        pk.z = pack_bf16(v[4], v[5]);
        pk.w = pack_bf16(v[6], v[7]);
        *(uint4*)&lds16[(1 + n) * 8] = pk;
    }
    __syncthreads();

    // ---- phase 4: main loop (8 tiles per wave), prefetched gather indices ----
    const char* slabp = (const char*)lds16;
    float* outb = out + (size_t)blockIdx.x * (COUT * NNODES);

    const int  rA   = (quad + 1) & 3;
    const bool q3f  = (quad == 3);
    const bool isq0 = (quad == 0);
    const bool isq1 = (quad == 1);
    const bool isq2 = (quad == 2);
    // i0 byte delta: q0 center 0, q1 d- -1024, q2 d+ +1024, q3 h- -128
    const int c0q = isq0 ? 0 : isq1 ? -1024 : isq2 ? 1024 : -128;
    // i1 byte delta (q<3): q0 h+ +128, q1 w- -16, q2 w+ +16
    const int c1q = isq0 ? 128 : isq1 ? -16 : 16;
    const int w   = r16 & 7;
    const bool p1w = isq1 ? (w > 0) : (isq2 ? (w < 7) : false);
    const int* rrow = rand_idx + rA;

    const int t0 = wave * 8;
    int gA = rrow[(t0 * 16 + r16) * RR];
    int gB = rrow[(t0 * 16 + r16) * RR + 4];

#pragma unroll 4
    for (int tt = 0; tt < 8; ++tt) {
        const int t = t0 + tt;
        const int m = t * 16 + r16;
        const int base = 16 + m * 16;
        const int hh = (m >> 3) & 7;

        const int curA = gA, curB = gB;
        const int mn = (tt < 7) ? (m + 16) : m;    // clamp to stay in-bounds
        gA = rrow[mn * RR];
        gB = rrow[mn * RR + 4];

        const int offA = 16 + curA * 16;
        const int offB = 16 + curB * 16;

        const bool p0 = isq0 | (isq1 & (t >= 4)) | (isq2 & (t < 28)) | (q3f & (hh > 0));
        const bool p1 = p1w | (isq0 & (hh < 7));
        const int off0 = p0 ? (base + c0q) : 0;
        const int off1 = q3f ? offA : (p1 ? (base + c1q) : 0);
        const int off2 = q3f ? offB : offA;
        const int off3 = q3f ? 0 : offB;

        union { uint4 u; short8 s; } r0, r1, r2, r3;   // 4x ds_read_b128
        r0.u = *(const uint4*)(slabp + off0);
        r1.u = *(const uint4*)(slabp + off1);
        r2.u = *(const uint4*)(slabp + off2);
        r3.u = *(const uint4*)(slabp + off3);

        floatx4 acc_a = {bias, bias, bias, bias};
        floatx4 acc_b = {0.0f, 0.0f, 0.0f, 0.0f};
        acc_a = __builtin_amdgcn_mfma_f32_16x16x32_bf16(r0.s, bfrag[0], acc_a, 0, 0, 0);
        acc_b = __builtin_amdgcn_mfma_f32_16x16x32_bf16(r2.s, bfrag[2], acc_b, 0, 0, 0);
        acc_a = __builtin_amdgcn_mfma_f32_16x16x32_bf16(r1.s, bfrag[1], acc_a, 0, 0, 0);
        acc_b = __builtin_amdgcn_mfma_f32_16x16x32_bf16(r3.s, bfrag[3], acc_b, 0, 0, 0);

        // C/D: col=lane&15 (=o), row=quad*4+reg (node within 16-tile)
        if (r16 < 8) {
            float4 res;
            res.x = acc_a.x + acc_b.x;
            res.y = acc_a.y + acc_b.y;
            res.z = acc_a.z + acc_b.z;
            res.w = acc_a.w + acc_b.w;
            *(float4*)(outb + r16 * NNODES + t * 16 + quad * 4) = res;
        }
    }
}

extern "C" void kernel_launch(void* const* d_in, const int* in_sizes, int n_in,
                              void* d_out, int out_size, void* d_ws, size_t ws_size,
                              hipStream_t stream) {
    const float* x       = (const float*)d_in[0];
    const float* conv_w  = (const float*)d_in[1];
    const float* conv_b  = (const float*)d_in[2];
    const float* mix_w   = (const float*)d_in[3];
    const float* mix_b   = (const float*)d_in[4];
    const float* alpha_p = (const float*)d_in[5];
    const int*   rand_i  = (const int*)d_in[6];
    float* out = (float*)d_out;

    const int BT = in_sizes[0] / (CIN * NNODES);   // 2048

    hybrid3d_v5<<<BT, 256, 0, stream>>>(x, conv_w, conv_b, mix_w, mix_b,
                                        alpha_p, rand_i, out);
}